// Round 16
// baseline (294.680 us; speedup 1.0000x reference)
//
#include <hip/hip_runtime.h>
#include <hip/hip_bf16.h>
#include <stdint.h>

// EvolvedLoopLinear: out[b,j] = sum_i x[b,i]*W[j,i] + b[j]
// M=8192, N=4096, K=4096. fp32 in/out, bf16 MFMA compute.
// Round 16: 4 waves/SIMD (the untested axis). 1024 threads = 16 waves
// (4M x 4N), per-wave 64x64 (acc=64 regs -> ~120 total, 4 waves/SIMD).
// Tile stays 256x256 (FETCH unchanged vs champion, unlike r11). BK=32,
// triple-buffer 96 KiB, distance-2, ONE barrier/tile, counted vmcnt(2)
// (r10 skeleton, correctness-proven) + r11/r14 paired-row LDS layout
// (HW-measured 0 conflicts at BK=32 — fixes r10's conflict bug).
// Mechanism: during any wave's ds_read window, 3 sibling waves on the
// SIMD keep the MFMA pipe fed (m114 TLP overlap) — the thing 2-wave
// lockstep structurally cannot do (r5-r15 plateau).

typedef __bf16 bf16_t;
typedef __bf16 bf16x8 __attribute__((ext_vector_type(8)));
typedef float  f32x4  __attribute__((ext_vector_type(4)));

#define M_DIM 8192
#define N_DIM 4096
#define K_DIM 4096
#define NT    (K_DIM / 32)   // 128 K-tiles of BK=32
#define BUFE  16384          // elements/buffer (32 KB): A 8192 | B 8192

#define GLD16(gp, lp) __builtin_amdgcn_global_load_lds(                    \
    (const __attribute__((address_space(1))) void*)(gp),                   \
    (__attribute__((address_space(3))) void*)(lp), 16, 0, 0)

#define MFMA(a, b, c) __builtin_amdgcn_mfma_f32_16x16x32_bf16((a), (b), (c), 0, 0, 0)

#define FENCE() asm volatile("" ::: "memory")

// ---------------- fp32 -> bf16 convert (vectorized, grid-stride) -----------
__global__ void __launch_bounds__(256) cvt_f32_bf16(
    const float* __restrict__ in, bf16_t* __restrict__ out, long n8)
{
    long i0 = (long)blockIdx.x * blockDim.x + threadIdx.x;
    long stride = (long)gridDim.x * blockDim.x;
    for (long i = i0; i < n8; i += stride) {
        const float4* p = (const float4*)(in + i * 8);
        float4 a = p[0];
        float4 b = p[1];
        bf16x8 o;
        o[0] = (bf16_t)a.x; o[1] = (bf16_t)a.y; o[2] = (bf16_t)a.z; o[3] = (bf16_t)a.w;
        o[4] = (bf16_t)b.x; o[5] = (bf16_t)b.y; o[6] = (bf16_t)b.z; o[7] = (bf16_t)b.w;
        *(bf16x8*)(out + i * 8) = o;
    }
}

// ---------------- 256x256 bf16 GEMM, 16 waves, triple-buffer BK=32 ---------
// Buffer q (16384 el): A (256 rows, paired-row [128][64]) @ q*BUFE,
//                      B (256 rows, paired-row [128][64]) @ +8192.
// Paired-row: row r, k -> ldsrow r>>1, off (r&1)*32 + k; 16B-chunk slot =
// chunk ^ (ldsrow&7)  [r11/r14 formulas, HW-verified 0 conflicts].
__global__ void __launch_bounds__(1024, 4) gemm_256_w16(
    const bf16_t* __restrict__ A, const bf16_t* __restrict__ B,
    const float* __restrict__ bias, float* __restrict__ C)
{
    __shared__ bf16_t sm[3 * BUFE];   // 96 KiB

    // XCD-aware bijective swizzle (gridDim = 512, divisible by 8)
    const int nwg = gridDim.x;
    const int bid = blockIdx.x;
    const int cpx = nwg >> 3;
    const int swz = (bid & 7) * cpx + (bid >> 3);
    const int NBN = N_DIM / 256;                       // 16
    const long blockM = (long)(swz / NBN) * 256;
    const long blockN = (long)(swz % NBN) * 256;

    const int t    = threadIdx.x;
    const int lane = t & 63;
    const int wid  = t >> 6;        // 16 waves: 4 (M) x 4 (N)
    const int wr   = wid >> 2;      // 0..3 -> 64 rows each
    const int wc   = wid & 3;       // 0..3 -> 64 cols each
    const int l15  = lane & 15;
    const int lk   = lane >> 4;     // 0..3

    // staging: thread t -> chunk t of each region (1024 chunks = 128
    // ldsrows x 8). sr = t>>3, slot s = t&7, global chunk c = s^(sr&7),
    // global row = 2*sr + (c>>2), k-chunk = (c&3)*8.  [r14 verbatim]
    const int sr = t >> 3;
    const int c  = (t & 7) ^ (sr & 7);
    const int grow = 2 * sr + (c >> 2);
    const int kc8  = (c & 3) * 8;
    const bf16_t* gA = A + (blockM + grow) * (long)K_DIM + kc8;
    const bf16_t* gB = B + (blockN + grow) * (long)K_DIM + kc8;
    const int dstT = t * 8;         // 16 B/thread; wave-uniform + lane*16 ✓

    // fragment reads [r14 formulas]: frag f row = wr*64 + f*16 + l15,
    // k = lk*8 -> ldsrow = wr*32 + f*8 + (l15>>1);
    // slot = ((l15&1)*4 + lk) ^ (l15>>1).
    const int slotA = (((((l15 & 1) << 2) + lk) ^ (l15 >> 1)) << 3);
    const int aBase = (wr * 32 + (l15 >> 1)) * 64 + slotA;          // +f*512
    const int bBase = 8192 + (wc * 32 + (l15 >> 1)) * 64 + slotA;   // +f*512

    f32x4 acc[4][4] = {};

#define STAGE(q, tk) do {                                                  \
    bf16_t* _l = (bf16_t*)sm + (q) * BUFE + dstT;                          \
    GLD16(gA + (long)(tk) * 32, _l);                                       \
    GLD16(gB + (long)(tk) * 32, _l + 8192); } while (0)

    // prologue: tile0 -> buf0, tile1 -> buf1 (fence-pinned issue order);
    // vmcnt(2) retires tile0's 2 loads, keeps tile1's in flight.
    STAGE(0, 0);
    FENCE();
    STAGE(1, 1);
    FENCE();
    asm volatile("s_waitcnt vmcnt(2)" ::: "memory");
    __builtin_amdgcn_sched_barrier(0);
    __builtin_amdgcn_s_barrier();
    FENCE();

    int r = 0, r2 = 2;   // compute buffer, stage buffer (= (tk+2)%3)
    for (int tk = 0; tk < NT; ++tk) {
        const bf16_t* sA = (const bf16_t*)sm + r * BUFE;

        // stage tile tk+2 into the buffer whose readers published at the
        // end-of-(tk-1) barrier
        if (tk + 2 < NT) STAGE(r2, tk + 2);
        FENCE();

        // 8 ds_reads + 16 MFMA; compiler counted lgkm waits; sibling
        // waves on the SIMD cover the read latency (4 waves/SIMD).
        bf16x8 b[4], a[4];
#pragma unroll
        for (int n = 0; n < 4; ++n) b[n] = *(const bf16x8*)(sA + bBase + n * 512);
#pragma unroll
        for (int m = 0; m < 4; ++m) a[m] = *(const bf16x8*)(sA + aBase + m * 512);
        __builtin_amdgcn_s_setprio(1);
#pragma unroll
        for (int m = 0; m < 4; ++m)
#pragma unroll
            for (int n = 0; n < 4; ++n)
                acc[m][n] = MFMA(a[m], b[n], acc[m][n]);
        __builtin_amdgcn_s_setprio(0);

        // counted drain: tile tk+1's 2 loads land; tk+2's 2 stay in flight
        if (tk < NT - 2) asm volatile("s_waitcnt vmcnt(2)" ::: "memory");
        else             asm volatile("s_waitcnt vmcnt(0)" ::: "memory");
        __builtin_amdgcn_sched_barrier(0);
        __builtin_amdgcn_s_barrier();
        FENCE();

        r  = (r  == 2) ? 0 : r  + 1;
        r2 = (r2 == 2) ? 0 : r2 + 1;
    }

#undef STAGE

    // epilogue: C/D layout col = lane&15, row = (lane>>4)*4 + j
    const long cb = blockN + wc * 64;
    float bv[4];
    long  cn[4];
#pragma unroll
    for (int n = 0; n < 4; ++n) {
        cn[n] = cb + n * 16 + l15;
        bv[n] = bias[cn[n]];
    }
#pragma unroll
    for (int m = 0; m < 4; ++m) {
        const long r0 = blockM + wr * 64 + m * 16 + lk * 4;
#pragma unroll
        for (int n = 0; n < 4; ++n)
#pragma unroll
            for (int j = 0; j < 4; ++j)
                C[(r0 + j) * (long)N_DIM + cn[n]] = acc[m][n][j] + bv[n];
    }
}

// ---------------- fp32 fallback (only if ws too small) ---------------------
__global__ void __launch_bounds__(256) gemm_f32_fallback(
    const float* __restrict__ A, const float* __restrict__ W,
    const float* __restrict__ bias, float* __restrict__ C)
{
    __shared__ float sA[64][17];
    __shared__ float sB[64][17];
    const int bm = blockIdx.y, bn = blockIdx.x;
    const int t = threadIdx.x;
    const int tx = t & 15, ty = t >> 4;
    const long row0 = (long)bm * 64, col0 = (long)bn * 64;
    float acc[4][4] = {};
    for (int kt = 0; kt < K_DIM; kt += 16) {
        const int r = t >> 2, c = (t & 3) * 4;
        float4 a4 = *(const float4*)&A[(row0 + r) * K_DIM + kt + c];
        float4 b4 = *(const float4*)&W[(col0 + r) * K_DIM + kt + c];
        sA[r][c] = a4.x; sA[r][c + 1] = a4.y; sA[r][c + 2] = a4.z; sA[r][c + 3] = a4.w;
        sB[r][c] = b4.x; sB[r][c + 1] = b4.y; sB[r][c + 2] = b4.z; sB[r][c + 3] = b4.w;
        __syncthreads();
#pragma unroll
        for (int kk = 0; kk < 16; ++kk) {
            float av[4], bv[4];
#pragma unroll
            for (int i = 0; i < 4; ++i) av[i] = sA[ty * 4 + i][kk];
#pragma unroll
            for (int j = 0; j < 4; ++j) bv[j] = sB[tx * 4 + j][kk];
#pragma unroll
            for (int i = 0; i < 4; ++i)
#pragma unroll
                for (int j = 0; j < 4; ++j) acc[i][j] += av[i] * bv[j];
        }
        __syncthreads();
    }
#pragma unroll
    for (int i = 0; i < 4; ++i)
#pragma unroll
        for (int j = 0; j < 4; ++j)
            C[(row0 + ty * 4 + i) * N_DIM + col0 + tx * 4 + j] =
                acc[i][j] + bias[col0 + tx * 4 + j];
}

extern "C" void kernel_launch(void* const* d_in, const int* in_sizes, int n_in,
                              void* d_out, int out_size, void* d_ws, size_t ws_size,
                              hipStream_t stream)
{
    const float* x = (const float*)d_in[0];   // [8192, 4096]
    const float* W = (const float*)d_in[1];   // [4096, 4096]
    const float* b = (const float*)d_in[2];   // [4096]
    float* out = (float*)d_out;               // [8192, 4096] fp32

    const long xe = (long)M_DIM * K_DIM;
    const long we = (long)N_DIM * K_DIM;
    const size_t need = (size_t)(xe + we) * sizeof(bf16_t);  // ~96 MiB

    if (ws_size >= need) {
        bf16_t* xb = (bf16_t*)d_ws;
        bf16_t* wb = xb + xe;
        cvt_f32_bf16<<<2048, 256, 0, stream>>>(x, xb, xe / 8);
        cvt_f32_bf16<<<1024, 256, 0, stream>>>(W, wb, we / 8);
        gemm_256_w16<<<(M_DIM / 256) * (N_DIM / 256), 1024, 0, stream>>>(xb, wb, b, out);
    } else {
        dim3 grid(N_DIM / 64, M_DIM / 64);
        gemm_f32_fallback<<<grid, 256, 0, stream>>>(x, W, b, out);
    }
}